// Round 8
// baseline (58.344 us; speedup 1.0000x reference)
//
#include <hip/hip_runtime.h>
#include <hip/hip_bf16.h>

#define HD 64
#define LSEQ 2048
#define NBATCH 1024
#define NSLOTS 8

// Single regular kernel, ZERO cross-block dependencies (coop launch and
// spin-flag handshakes abort this harness; measured R3/R4/R5).
// Each of 128 blocks (512 threads, 8 waves):
//   1. issues seq loads for its 8 rows (wave w -> row blockIdx*8+w)
//   2. redundantly builds the full 64-token table (h, qi, sk, score) in LDS
//   3. each wave independently: histogram -> rank -> slot fill -> two-stage
//      attention -> output row.
// R7 fix vs R6: explicit __syncthreads() at every same-wave LDS write->read
// window in phase 3, and no float4 type-punning on LDS reads — the compiler
// may reorder a punned ds_read_b128 across per-lane ds_write_b32 (R6's 0.30
// absmax). Hardware DS is in-order per wave; the barriers pin the compiler.
__global__ __launch_bounds__(512) void fused_kernel(
    const int* __restrict__ seq,
    const float* __restrict__ embed, const float* __restrict__ w1, const float* __restrict__ b1,
    const float* __restrict__ w2, const float* __restrict__ b2,
    const float* __restrict__ gamma, const float* __restrict__ beta,
    const float* __restrict__ gate_w, const float* __restrict__ gate_b,
    const float* __restrict__ qi_w, const float* __restrict__ qi_b,
    const float* __restrict__ sk_w, const float* __restrict__ sk_b,
    const float* __restrict__ qr_w, const float* __restrict__ qr_b,
    const float* __restrict__ out_w, const float* __restrict__ out_b,
    float* __restrict__ out)
{
    const int tid  = threadIdx.x;                         // 0..511
    const int w    = tid >> 6;                            // wave 0..7
    const int lane = tid & 63;
    const int wu   = __builtin_amdgcn_readfirstlane(w);   // SGPR wave id
    const int row  = blockIdx.x * 8 + wu;                 // this wave's batch row

    // +1-padded rows -> all row/column LDS accesses are 2-way-or-free on banks.
    __shared__ float E [64][65];
    __shared__ float T1[64][129];
    __shared__ float X [64][65];
    __shared__ float H [64][65];
    __shared__ float QI[64][65];
    __shared__ float SK[64][65];
    __shared__ float score_s[64];
    __shared__ int   hist[8][64];
    __shared__ int   order_s[8][64];
    __shared__ int   slot_s[8][NSLOTS];
    __shared__ float rbuf[8][64];

    // ---- 1. seq prefetch: 8 coalesced int4 per lane (whole row per wave) ----
    const int4* srow4 = (const int4*)(seq + (size_t)row * LSEQ);
    int4 q[8];
    #pragma unroll
    for (int i = 0; i < 8; ++i) q[i] = srow4[lane + 64 * i];

    // ---- 2a. embed -> LDS ----
    for (int i = tid; i < 64 * HD; i += 512) E[i >> 6][i & 63] = embed[i];
    __syncthreads();

    // ---- 2b. T1 = relu(E @ w1^T + b1) : wave w owns j in [wu*16, wu*16+16) ----
    {
        const int j0 = wu * 16;
        float acc[16];
        #pragma unroll
        for (int jj = 0; jj < 16; ++jj) acc[jj] = b1[j0 + jj];
        #pragma unroll 1
        for (int half = 0; half < 2; ++half) {
            float er[32];
            #pragma unroll
            for (int c = 0; c < 32; ++c) er[c] = E[lane][half * 32 + c];
            #pragma unroll
            for (int jj = 0; jj < 16; ++jj) {
                const float* w1r = w1 + (j0 + jj) * HD + half * 32;  // wave-uniform -> s_load
                #pragma unroll
                for (int c = 0; c < 32; ++c)
                    acc[jj] = fmaf(er[c], w1r[c], acc[jj]);
            }
        }
        #pragma unroll
        for (int jj = 0; jj < 16; ++jj)
            T1[lane][j0 + jj] = fmaxf(acc[jj], 0.0f);
    }
    __syncthreads();

    // ---- 2c. X = E + b2 + T1 @ w2^T : wave w owns i in [wu*8, wu*8+8) ----
    {
        const int i0 = wu * 8;
        float acc[8];
        #pragma unroll
        for (int ii = 0; ii < 8; ++ii) acc[ii] = E[lane][i0 + ii] + b2[i0 + ii];
        #pragma unroll 1
        for (int quar = 0; quar < 4; ++quar) {
            float tr[32];
            #pragma unroll
            for (int c = 0; c < 32; ++c) tr[c] = T1[lane][quar * 32 + c];
            #pragma unroll
            for (int ii = 0; ii < 8; ++ii) {
                const float* w2r = w2 + (i0 + ii) * 2 * HD + quar * 32;  // s_load
                #pragma unroll
                for (int c = 0; c < 32; ++c)
                    acc[ii] = fmaf(tr[c], w2r[c], acc[ii]);
            }
        }
        #pragma unroll
        for (int ii = 0; ii < 8; ++ii) X[lane][i0 + ii] = acc[ii];
    }
    __syncthreads();

    // ---- 2d. LayerNorm + gate score: 8 lanes per token (64 tokens x 8) ----
    {
        const int v  = tid >> 3;   // token
        const int g  = tid & 7;    // 8-elem sub-group (within one wave)
        const int k0 = g * 8;
        float xr[8];
        #pragma unroll
        for (int d = 0; d < 8; ++d) xr[d] = X[v][k0 + d];
        float s = 0.0f;
        #pragma unroll
        for (int d = 0; d < 8; ++d) s += xr[d];
        s += __shfl_xor(s, 1); s += __shfl_xor(s, 2); s += __shfl_xor(s, 4);
        const float mu = s * (1.0f / 64.0f);
        float vs = 0.0f;
        #pragma unroll
        for (int d = 0; d < 8; ++d) { float dd = xr[d] - mu; vs = fmaf(dd, dd, vs); }
        vs += __shfl_xor(vs, 1); vs += __shfl_xor(vs, 2); vs += __shfl_xor(vs, 4);
        const float rstd = rsqrtf(vs * (1.0f / 64.0f) + 1e-5f);
        float sp = 0.0f;
        #pragma unroll
        for (int d = 0; d < 8; ++d) {
            const int k = k0 + d;
            const float h = (xr[d] - mu) * rstd * gamma[k] + beta[k];
            H[v][k] = h;
            sp = fmaf(h, gate_w[k], sp);
        }
        sp += __shfl_xor(sp, 1); sp += __shfl_xor(sp, 2); sp += __shfl_xor(sp, 4);
        if (g == 0) score_s[v] = sp + gate_b[0];
    }
    __syncthreads();

    // ---- 2e. QI = H @ qi_w^T + qi_b (waves 0-3), SK likewise (waves 4-7) ----
    {
        const bool isqi = (wu < 4);
        const int  i0   = (wu & 3) * 16;
        const float* Wm = isqi ? qi_w : sk_w;
        const float* Bm = isqi ? qi_b : sk_b;
        float acc[16];
        #pragma unroll
        for (int ii = 0; ii < 16; ++ii) acc[ii] = Bm[i0 + ii];
        #pragma unroll 1
        for (int half = 0; half < 2; ++half) {
            float hr[32];
            #pragma unroll
            for (int c = 0; c < 32; ++c) hr[c] = H[lane][half * 32 + c];
            #pragma unroll
            for (int ii = 0; ii < 16; ++ii) {
                const float* Wr = Wm + (i0 + ii) * HD + half * 32;  // s_load
                #pragma unroll
                for (int c = 0; c < 32; ++c)
                    acc[ii] = fmaf(hr[c], Wr[c], acc[ii]);
            }
        }
        float (*DST)[65] = isqi ? QI : SK;
        #pragma unroll
        for (int ii = 0; ii < 16; ++ii) DST[lane][i0 + ii] = acc[ii];
    }
    __syncthreads();

    // ---- 3. Per-wave row pipeline with explicit cross-step barriers ----
    hist[w][lane] = 0;   // same-wave row; ordered before same-wave atomics
    #pragma unroll
    for (int i = 0; i < 8; ++i) {
        atomicAdd(&hist[w][q[i].x], 1); atomicAdd(&hist[w][q[i].y], 1);
        atomicAdd(&hist[w][q[i].z], 1); atomicAdd(&hist[w][q[i].w], 1);
    }
    const int last = __shfl(q[7].w, 63);   // token at position 2047

    const float sc = score_s[lane];
    int rank = 0;
    #pragma unroll
    for (int u = 0; u < 64; ++u) {
        float su = __shfl(sc, u);
        if (su > sc || (su == sc && u < lane)) ++rank;
    }
    order_s[w][rank] = lane;
    __syncthreads();                        // B1: hist atomics + order_s visible

    const int tok  = order_s[w][lane];      // token with rank 'lane'
    const int cntr = hist[w][tok];

    int inc = cntr;
    #pragma unroll
    for (int off = 1; off < 64; off <<= 1) {
        int v2 = __shfl_up(inc, off);
        if (lane >= off) inc += v2;
    }
    const int cum = inc - cntr;             // exclusive prefix in rank order
    #pragma unroll
    for (int s = 0; s < NSLOTS; ++s)
        if (s >= cum && s < cum + cntr) slot_s[w][s] = tok;
    __syncthreads();                        // B2: slot_s visible

    int st_[NSLOTS];
    #pragma unroll
    for (int s = 0; s < NSLOTS; ++s) st_[s] = slot_s[w][s];

    const float scale = 0.125f;             // 1/sqrt(64)
    const float qk = QI[last][lane];

    float mrow[NSLOTS], skrow[NSLOTS];
    #pragma unroll
    for (int s = 0; s < NSLOTS; ++s) {
        mrow[s]  = H[st_[s]][lane];
        skrow[s] = SK[st_[s]][lane];
    }

    // Stage 1: r = softmax(slot_keys . q_init * scale)
    float p[NSLOTS];
    #pragma unroll
    for (int s = 0; s < NSLOTS; ++s) p[s] = skrow[s] * qk;
    #pragma unroll
    for (int off = 1; off < 64; off <<= 1) {
        #pragma unroll
        for (int s = 0; s < NSLOTS; ++s) p[s] += __shfl_xor(p[s], off);
    }
    #pragma unroll
    for (int s = 0; s < NSLOTS; ++s) p[s] *= scale;
    float mx = p[0];
    #pragma unroll
    for (int s = 1; s < NSLOTS; ++s) mx = fmaxf(mx, p[s]);
    float sum = 0.0f, r[NSLOTS];
    #pragma unroll
    for (int s = 0; s < NSLOTS; ++s) { r[s] = expf(p[s] - mx); sum += r[s]; }
    float inv = 1.0f / sum;
    float readk = 0.0f;
    #pragma unroll
    for (int s = 0; s < NSLOTS; ++s) readk = fmaf(r[s] * inv, mrow[s], readk);
    rbuf[w][lane] = readk;
    __syncthreads();                        // B3: read vector visible

    // q_refined = q_init + qr_b + qr_w . read
    // (float4 only on read-only GLOBAL weights; LDS read back as scalar float)
    float qref = qk + qr_b[lane];
    {
        const float4* wr = (const float4*)(qr_w + lane * HD);
        #pragma unroll
        for (int j4 = 0; j4 < HD / 4; ++j4) {
            float4 a = wr[j4];
            qref = fmaf(a.x, rbuf[w][4 * j4 + 0], qref);
            qref = fmaf(a.y, rbuf[w][4 * j4 + 1], qref);
            qref = fmaf(a.z, rbuf[w][4 * j4 + 2], qref);
            qref = fmaf(a.w, rbuf[w][4 * j4 + 3], qref);
        }
    }

    // Stage 2
    float p2[NSLOTS];
    #pragma unroll
    for (int s = 0; s < NSLOTS; ++s) p2[s] = mrow[s] * qref;
    #pragma unroll
    for (int off = 1; off < 64; off <<= 1) {
        #pragma unroll
        for (int s = 0; s < NSLOTS; ++s) p2[s] += __shfl_xor(p2[s], off);
    }
    #pragma unroll
    for (int s = 0; s < NSLOTS; ++s) p2[s] *= scale;
    float mx2 = p2[0];
    #pragma unroll
    for (int s = 1; s < NSLOTS; ++s) mx2 = fmaxf(mx2, p2[s]);
    float sum2 = 0.0f, aa[NSLOTS];
    #pragma unroll
    for (int s = 0; s < NSLOTS; ++s) { aa[s] = expf(p2[s] - mx2); sum2 += aa[s]; }
    float inv2 = 1.0f / sum2;
    float pooled = 0.0f;
    #pragma unroll
    for (int s = 0; s < NSLOTS; ++s) pooled = fmaf(aa[s] * inv2, mrow[s], pooled);
    __syncthreads();                        // B4a: all reads of rbuf (readk) done
    rbuf[w][lane] = pooled;
    __syncthreads();                        // B4b: pooled vector visible

    // out[row][v] = out_b[v] + out_w[v,:] . pooled
    float acc = out_b[lane];
    {
        const float4* wo = (const float4*)(out_w + lane * HD);
        #pragma unroll
        for (int k4 = 0; k4 < HD / 4; ++k4) {
            float4 a = wo[k4];
            acc = fmaf(a.x, rbuf[w][4 * k4 + 0], acc);
            acc = fmaf(a.y, rbuf[w][4 * k4 + 1], acc);
            acc = fmaf(a.z, rbuf[w][4 * k4 + 2], acc);
            acc = fmaf(a.w, rbuf[w][4 * k4 + 3], acc);
        }
    }
    out[(size_t)row * HD + lane] = acc;
}

extern "C" void kernel_launch(void* const* d_in, const int* in_sizes, int n_in,
                              void* d_out, int out_size, void* d_ws, size_t ws_size,
                              hipStream_t stream) {
    const int*   seq    = (const int*)  d_in[0];
    const float* embed  = (const float*)d_in[1];
    const float* w1     = (const float*)d_in[2];
    const float* b1     = (const float*)d_in[3];
    const float* w2     = (const float*)d_in[4];
    const float* b2     = (const float*)d_in[5];
    const float* gamma  = (const float*)d_in[6];
    const float* beta   = (const float*)d_in[7];
    const float* gate_w = (const float*)d_in[8];
    const float* gate_b = (const float*)d_in[9];
    const float* qi_w   = (const float*)d_in[10];
    const float* qi_b   = (const float*)d_in[11];
    const float* sk_w   = (const float*)d_in[12];
    const float* sk_b   = (const float*)d_in[13];
    const float* qr_w   = (const float*)d_in[14];
    const float* qr_b   = (const float*)d_in[15];
    const float* out_w  = (const float*)d_in[16];
    const float* out_b  = (const float*)d_in[17];

    hipLaunchKernelGGL(fused_kernel, dim3(NBATCH / 8), dim3(512), 0, stream,
                       seq, embed, w1, b1, w2, b2, gamma, beta, gate_w, gate_b,
                       qi_w, qi_b, sk_w, sk_b, qr_w, qr_b, out_w, out_b,
                       (float*)d_out);
}

// Round 9
// 23.142 us; speedup vs baseline: 2.5211x; 2.5211x over previous
//
#include <hip/hip_runtime.h>
#include <hip/hip_bf16.h>

#define HD 64
#define LSEQ 2048
#define NBATCH 1024
#define NSLOTS 8

// ---------------- Kernel 1: per-token tables (R2-verified, unchanged) ----------------
__global__ __launch_bounds__(128) void build_tables_kernel(
    const float* __restrict__ embed, const float* __restrict__ w1, const float* __restrict__ b1,
    const float* __restrict__ w2, const float* __restrict__ b2,
    const float* __restrict__ gamma, const float* __restrict__ beta,
    const float* __restrict__ gate_w, const float* __restrict__ gate_b,
    const float* __restrict__ qi_w, const float* __restrict__ qi_b,
    const float* __restrict__ sk_w, const float* __restrict__ sk_b,
    float* __restrict__ h_table, float* __restrict__ qi_table, float* __restrict__ sk_table,
    float* __restrict__ score)
{
    const int v = blockIdx.x;
    const int tid = threadIdx.x;

    __shared__ __align__(16) float E[HD];
    __shared__ __align__(16) float T1[2 * HD];
    __shared__ __align__(16) float Hrow[HD];

    if (tid < HD) E[tid] = embed[v * HD + tid];
    __syncthreads();
    {
        const float4* w1r = (const float4*)(w1 + tid * HD);
        const float4* E4  = (const float4*)E;
        float t = b1[tid];
        #pragma unroll
        for (int k = 0; k < HD / 4; ++k) {
            float4 a = w1r[k], e = E4[k];
            t = fmaf(a.x, e.x, t); t = fmaf(a.y, e.y, t);
            t = fmaf(a.z, e.z, t); t = fmaf(a.w, e.w, t);
        }
        T1[tid] = fmaxf(t, 0.0f);
    }
    __syncthreads();
    if (tid < HD) {
        const float4* w2r = (const float4*)(w2 + tid * 2 * HD);
        const float4* T4  = (const float4*)T1;
        float x = E[tid] + b2[tid];
        #pragma unroll
        for (int j = 0; j < 2 * HD / 4; ++j) {
            float4 a = w2r[j], t = T4[j];
            x = fmaf(a.x, t.x, x); x = fmaf(a.y, t.y, x);
            x = fmaf(a.z, t.z, x); x = fmaf(a.w, t.w, x);
        }
        float mu = x;
        #pragma unroll
        for (int off = 1; off < 64; off <<= 1) mu += __shfl_xor(mu, off);
        mu *= (1.0f / 64.0f);
        float d = x - mu;
        float var = d * d;
        #pragma unroll
        for (int off = 1; off < 64; off <<= 1) var += __shfl_xor(var, off);
        var *= (1.0f / 64.0f);
        float h = d * rsqrtf(var + 1e-5f) * gamma[tid] + beta[tid];
        Hrow[tid] = h;
        h_table[v * HD + tid] = h;
        float sc = h * gate_w[tid];
        #pragma unroll
        for (int off = 1; off < 64; off <<= 1) sc += __shfl_xor(sc, off);
        if (tid == 0) score[v] = sc + gate_b[0];
    }
    __syncthreads();
    {
        const int i = tid & 63;
        const float* W  = (tid < HD) ? qi_w : sk_w;
        const float* Bv = (tid < HD) ? qi_b : sk_b;
        const float4* Wr = (const float4*)(W + i * HD);
        const float4* H4 = (const float4*)Hrow;
        float acc = Bv[i];
        #pragma unroll
        for (int k = 0; k < HD / 4; ++k) {
            float4 a = Wr[k], h = H4[k];
            acc = fmaf(a.x, h.x, acc); acc = fmaf(a.y, h.y, acc);
            acc = fmaf(a.z, h.z, acc); acc = fmaf(a.w, h.w, acc);
        }
        float* dst = (tid < HD) ? qi_table : sk_table;
        dst[v * HD + i] = acc;
    }
}

// ---------------- Kernel 2: main, 1 row per wave ----------------
// 256 blocks x 256 threads; wave w -> batch row blockIdx*4 + w.
// Wave-local pipeline with the R7-verified barrier skeleton (B1..B4).
__global__ __launch_bounds__(256) void main_kernel(
    const int* __restrict__ seq,
    const float* __restrict__ h_table, const float* __restrict__ qi_table,
    const float* __restrict__ sk_table,
    const float* __restrict__ qr_w, const float* __restrict__ qr_b,
    const float* __restrict__ out_w, const float* __restrict__ out_b,
    const float* __restrict__ score,
    float* __restrict__ out)
{
    const int tid  = threadIdx.x;                        // 0..255
    const int w    = tid >> 6;                           // wave 0..3
    const int lane = tid & 63;
    const int row  = blockIdx.x * 4 + w;                 // this wave's batch row

    __shared__ int   hist[4][64];
    __shared__ int   order_s[4][64];
    __shared__ int   slot_s[4][NSLOTS];
    __shared__ float rbuf[4][64];

    // coalesced seq row load: 8 int4 per lane (whole 2048-token row per wave)
    const int4* srow4 = (const int4*)(seq + (size_t)row * LSEQ);
    int4 q[8];
    #pragma unroll
    for (int i = 0; i < 8; ++i) q[i] = srow4[lane + 64 * i];

    const float sc = score[lane];    // issued early; L2-hit broadcast

    // per-wave histogram (same-wave DS ops are in program order)
    hist[w][lane] = 0;
    #pragma unroll
    for (int i = 0; i < 8; ++i) {
        atomicAdd(&hist[w][q[i].x], 1); atomicAdd(&hist[w][q[i].y], 1);
        atomicAdd(&hist[w][q[i].z], 1); atomicAdd(&hist[w][q[i].w], 1);
    }
    const int last = __shfl(q[7].w, 63);   // token at position 2047

    // rank by (score desc, token asc) via shuffles
    int rank = 0;
    #pragma unroll
    for (int u = 0; u < 64; ++u) {
        float su = __shfl(sc, u);
        if (su > sc || (su == sc && u < lane)) ++rank;
    }
    order_s[w][rank] = lane;
    __syncthreads();                        // B1: hist + order_s pinned

    const int tok  = order_s[w][lane];      // token with rank 'lane'
    const int cntr = hist[w][tok];

    int inc = cntr;
    #pragma unroll
    for (int off = 1; off < 64; off <<= 1) {
        int v2 = __shfl_up(inc, off);
        if (lane >= off) inc += v2;
    }
    const int cum = inc - cntr;             // exclusive prefix in rank order
    #pragma unroll
    for (int s = 0; s < NSLOTS; ++s)
        if (s >= cum && s < cum + cntr) slot_s[w][s] = tok;
    __syncthreads();                        // B2: slot_s pinned

    int st_[NSLOTS];
    #pragma unroll
    for (int s = 0; s < NSLOTS; ++s) st_[s] = slot_s[w][s];

    const float scale = 0.125f;             // 1/sqrt(64)
    const float qk = qi_table[last * HD + lane];

    float mrow[NSLOTS], skrow[NSLOTS];
    #pragma unroll
    for (int s = 0; s < NSLOTS; ++s) {
        mrow[s]  = h_table[st_[s] * HD + lane];     // 256B coalesced, L2-hit
        skrow[s] = sk_table[st_[s] * HD + lane];
    }

    // Stage 1: r = softmax(slot_keys . q_init * scale)
    float p[NSLOTS];
    #pragma unroll
    for (int s = 0; s < NSLOTS; ++s) p[s] = skrow[s] * qk;
    #pragma unroll
    for (int off = 1; off < 64; off <<= 1) {
        #pragma unroll
        for (int s = 0; s < NSLOTS; ++s) p[s] += __shfl_xor(p[s], off);
    }
    #pragma unroll
    for (int s = 0; s < NSLOTS; ++s) p[s] *= scale;
    float mx = p[0];
    #pragma unroll
    for (int s = 1; s < NSLOTS; ++s) mx = fmaxf(mx, p[s]);
    float sum = 0.0f, r[NSLOTS];
    #pragma unroll
    for (int s = 0; s < NSLOTS; ++s) { r[s] = expf(p[s] - mx); sum += r[s]; }
    float inv = 1.0f / sum;
    float readk = 0.0f;
    #pragma unroll
    for (int s = 0; s < NSLOTS; ++s) readk = fmaf(r[s] * inv, mrow[s], readk);
    rbuf[w][lane] = readk;
    __syncthreads();                        // B3: read vector pinned

    // q_refined = q_init + qr_b + qr_w . read
    // (float4 only on read-only global weights; LDS read back scalar)
    float qref = qk + qr_b[lane];
    {
        const float4* wr = (const float4*)(qr_w + lane * HD);
        #pragma unroll
        for (int j4 = 0; j4 < HD / 4; ++j4) {
            float4 a = wr[j4];
            qref = fmaf(a.x, rbuf[w][4 * j4 + 0], qref);
            qref = fmaf(a.y, rbuf[w][4 * j4 + 1], qref);
            qref = fmaf(a.z, rbuf[w][4 * j4 + 2], qref);
            qref = fmaf(a.w, rbuf[w][4 * j4 + 3], qref);
        }
    }

    // Stage 2
    float p2[NSLOTS];
    #pragma unroll
    for (int s = 0; s < NSLOTS; ++s) p2[s] = mrow[s] * qref;
    #pragma unroll
    for (int off = 1; off < 64; off <<= 1) {
        #pragma unroll
        for (int s = 0; s < NSLOTS; ++s) p2[s] += __shfl_xor(p2[s], off);
    }
    #pragma unroll
    for (int s = 0; s < NSLOTS; ++s) p2[s] *= scale;
    float mx2 = p2[0];
    #pragma unroll
    for (int s = 1; s < NSLOTS; ++s) mx2 = fmaxf(mx2, p2[s]);
    float sum2 = 0.0f, aa[NSLOTS];
    #pragma unroll
    for (int s = 0; s < NSLOTS; ++s) { aa[s] = expf(p2[s] - mx2); sum2 += aa[s]; }
    float inv2 = 1.0f / sum2;
    float pooled = 0.0f;
    #pragma unroll
    for (int s = 0; s < NSLOTS; ++s) pooled = fmaf(aa[s] * inv2, mrow[s], pooled);
    __syncthreads();                        // B4a: all readk reads done
    rbuf[w][lane] = pooled;
    __syncthreads();                        // B4b: pooled vector pinned

    // out[row][v] = out_b[v] + out_w[v,:] . pooled
    float acc = out_b[lane];
    {
        const float4* wo = (const float4*)(out_w + lane * HD);
        #pragma unroll
        for (int k4 = 0; k4 < HD / 4; ++k4) {
            float4 a = wo[k4];
            acc = fmaf(a.x, rbuf[w][4 * k4 + 0], acc);
            acc = fmaf(a.y, rbuf[w][4 * k4 + 1], acc);
            acc = fmaf(a.z, rbuf[w][4 * k4 + 2], acc);
            acc = fmaf(a.w, rbuf[w][4 * k4 + 3], acc);
        }
    }
    out[(size_t)row * HD + lane] = acc;
}

extern "C" void kernel_launch(void* const* d_in, const int* in_sizes, int n_in,
                              void* d_out, int out_size, void* d_ws, size_t ws_size,
                              hipStream_t stream) {
    const int*   seq    = (const int*)  d_in[0];
    const float* embed  = (const float*)d_in[1];
    const float* w1     = (const float*)d_in[2];
    const float* b1     = (const float*)d_in[3];
    const float* w2     = (const float*)d_in[4];
    const float* b2     = (const float*)d_in[5];
    const float* gamma  = (const float*)d_in[6];
    const float* beta   = (const float*)d_in[7];
    const float* gate_w = (const float*)d_in[8];
    const float* gate_b = (const float*)d_in[9];
    const float* qi_w   = (const float*)d_in[10];
    const float* qi_b   = (const float*)d_in[11];
    const float* sk_w   = (const float*)d_in[12];
    const float* sk_b   = (const float*)d_in[13];
    const float* qr_w   = (const float*)d_in[14];
    const float* qr_b   = (const float*)d_in[15];
    const float* out_w  = (const float*)d_in[16];
    const float* out_b  = (const float*)d_in[17];

    float* ws = (float*)d_ws;
    float* h_table  = ws;            // 4096 floats
    float* qi_table = ws + 4096;     // 4096
    float* sk_table = ws + 8192;     // 4096
    float* score    = ws + 12288;    // 64

    hipLaunchKernelGGL(build_tables_kernel, dim3(64), dim3(128), 0, stream,
                       embed, w1, b1, w2, b2, gamma, beta, gate_w, gate_b,
                       qi_w, qi_b, sk_w, sk_b,
                       h_table, qi_table, sk_table, score);

    hipLaunchKernelGGL(main_kernel, dim3(NBATCH / 4), dim3(256), 0, stream,
                       seq, h_table, qi_table, sk_table,
                       qr_w, qr_b, out_w, out_b, score, (float*)d_out);
}